// Round 1
// baseline (10763.580 us; speedup 1.0000x reference)
//
#include <hip/hip_runtime.h>
#include <math.h>

#define T_STEPS 128
#define B_SZ 128
#define D_SZ 1024
#define H_SZ 1024
#define G4 4096  // 4*H

__device__ __forceinline__ float sigf(float x) { return 1.0f / (1.0f + __expf(-x)); }

// ---------------------------------------------------------------------------
// Phase A: XW[m][n] = bias[n] + sum_d x[m][d] * W[d][n]   (m = t*B+b, n in 4H)
// 64x64 tile, K-tile 16, 256 threads, 4x4 per thread. fp32 VALU.
// ---------------------------------------------------------------------------
__global__ __launch_bounds__(256) void xw_gemm(const float* __restrict__ x,
                                               const float* __restrict__ W,
                                               const float* __restrict__ bias,
                                               float* __restrict__ xw) {
  __shared__ float As[16][64];  // [k][m] (transposed for b128 reads over m)
  __shared__ float Bs[16][64];  // [k][n]
  const int tid = threadIdx.x;
  const int n0 = blockIdx.x * 64;
  const int m0 = blockIdx.y * 64;
  const int tx = tid & 15;      // col group
  const int ty = tid >> 4;      // row group
  const int lr = tid >> 2;      // A stage: row 0..63
  const int lk = (tid & 3) * 4; // A stage: k quad
  const int br = tid >> 4;      // B stage: k row 0..15
  const int bc = (tid & 15) * 4;// B stage: col quad
  float acc[4][4] = {};
  for (int k0 = 0; k0 < D_SZ; k0 += 16) {
    float4 av = *(const float4*)&x[(size_t)(m0 + lr) * D_SZ + k0 + lk];
    float4 bv = *(const float4*)&W[(size_t)(k0 + br) * G4 + n0 + bc];
    __syncthreads();  // protect previous iteration's reads
    As[lk + 0][lr] = av.x;
    As[lk + 1][lr] = av.y;
    As[lk + 2][lr] = av.z;
    As[lk + 3][lr] = av.w;
    *(float4*)&Bs[br][bc] = bv;
    __syncthreads();
#pragma unroll
    for (int kk = 0; kk < 16; ++kk) {
      float4 a4 = *(const float4*)&As[kk][ty * 4];
      float4 b4 = *(const float4*)&Bs[kk][tx * 4];
      float aa[4] = {a4.x, a4.y, a4.z, a4.w};
      float bb[4] = {b4.x, b4.y, b4.z, b4.w};
#pragma unroll
      for (int i = 0; i < 4; ++i)
#pragma unroll
        for (int j = 0; j < 4; ++j) acc[i][j] += aa[i] * bb[j];
    }
  }
#pragma unroll
  for (int i = 0; i < 4; ++i) {
    const int m = m0 + ty * 4 + i;
#pragma unroll
    for (int j = 0; j < 4; ++j) {
      const int n = n0 + tx * 4 + j;
      xw[(size_t)m * G4 + n] = acc[i][j] + bias[n];
    }
  }
}

// ---------------------------------------------------------------------------
// Phase B: one LSTM step. Tile [16 b-rows x 32 j-cols], 4 gates per thread-col.
// h_used staged in LDS (reset mask applied); W read from global (L1/L2 reuse).
// Grid: (32 col-tiles, 8 row-tiles) = 256 blocks x 256 threads.
// ---------------------------------------------------------------------------
template <int HAS_XW>
__global__ __launch_bounds__(256) void lstm_step(
    const float* __restrict__ h_prev,  // [B,H]
    const float* __restrict__ c_prev,  // [B,H]
    const float* __restrict__ x_t,     // [B,D]   (only if !HAS_XW)
    const float* __restrict__ xw_t,    // [B,4H]  (only if HAS_XW)
    const float* __restrict__ W,       // [(D+H),4H]
    const float* __restrict__ bias,    // [4H]
    const float* __restrict__ reset_t, // [B]
    float* __restrict__ h_out,         // [B,H]
    float* __restrict__ c_out)         // [B,H]
{
  __shared__ float Hs[16][64];
  const int tid = threadIdx.x;
  const int tx = tid & 31;   // col within tile
  const int ty = tid >> 5;   // 0..7 -> 2 rows each
  const int j0 = blockIdx.x * 32;
  const int b0 = blockIdx.y * 16;
  const int j = j0 + tx;
  const float* Wh = W + (size_t)D_SZ * G4;
  const int sr = tid >> 4;         // staging row 0..15
  const int sc = (tid & 15) * 4;   // staging k quad
  const float mrow = 1.0f - reset_t[b0 + sr];
  float acc[2][4] = {};

  // recurrent part: K over H with Wh
  for (int k0 = 0; k0 < H_SZ; k0 += 64) {
    float4 hv = *(const float4*)&h_prev[(size_t)(b0 + sr) * H_SZ + k0 + sc];
    hv.x *= mrow; hv.y *= mrow; hv.z *= mrow; hv.w *= mrow;
    __syncthreads();
    *(float4*)&Hs[sr][sc] = hv;
    __syncthreads();
#pragma unroll 4
    for (int kk = 0; kk < 64; ++kk) {
      const float a0 = Hs[ty * 2][kk];
      const float a1 = Hs[ty * 2 + 1][kk];
      const float* wrow = &Wh[(size_t)(k0 + kk) * G4 + j];
      const float w0 = wrow[0];
      const float w1 = wrow[H_SZ];
      const float w2 = wrow[2 * H_SZ];
      const float w3 = wrow[3 * H_SZ];
      acc[0][0] += a0 * w0; acc[1][0] += a1 * w0;
      acc[0][1] += a0 * w1; acc[1][1] += a1 * w1;
      acc[0][2] += a0 * w2; acc[1][2] += a1 * w2;
      acc[0][3] += a0 * w3; acc[1][3] += a1 * w3;
    }
  }

  if (!HAS_XW) {
    // x part: K over D with W rows [0,D)
    for (int k0 = 0; k0 < D_SZ; k0 += 64) {
      float4 xv = *(const float4*)&x_t[(size_t)(b0 + sr) * D_SZ + k0 + sc];
      __syncthreads();
      *(float4*)&Hs[sr][sc] = xv;
      __syncthreads();
#pragma unroll 4
      for (int kk = 0; kk < 64; ++kk) {
        const float a0 = Hs[ty * 2][kk];
        const float a1 = Hs[ty * 2 + 1][kk];
        const float* wrow = &W[(size_t)(k0 + kk) * G4 + j];
        const float w0 = wrow[0];
        const float w1 = wrow[H_SZ];
        const float w2 = wrow[2 * H_SZ];
        const float w3 = wrow[3 * H_SZ];
        acc[0][0] += a0 * w0; acc[1][0] += a1 * w0;
        acc[0][1] += a0 * w1; acc[1][1] += a1 * w1;
        acc[0][2] += a0 * w2; acc[1][2] += a1 * w2;
        acc[0][3] += a0 * w3; acc[1][3] += a1 * w3;
      }
    }
  }

#pragma unroll
  for (int r = 0; r < 2; ++r) {
    const int b = b0 + ty * 2 + r;
    float gi = acc[r][0], gg = acc[r][1], gf = acc[r][2], go = acc[r][3];
    if (HAS_XW) {
      const float* xwrow = &xw_t[(size_t)b * G4 + j];
      gi += xwrow[0];
      gg += xwrow[H_SZ];
      gf += xwrow[2 * H_SZ];
      go += xwrow[3 * H_SZ];
    } else {
      gi += bias[j];
      gg += bias[H_SZ + j];
      gf += bias[2 * H_SZ + j];
      go += bias[3 * H_SZ + j];
    }
    const float m = 1.0f - reset_t[b];
    const float cu = c_prev[(size_t)b * H_SZ + j] * m;
    const float f = sigf(gf + 1.0f);
    const float cn = f * cu + sigf(gi) * tanhf(gg);
    const float hn = sigf(go) * tanhf(cn);
    h_out[(size_t)b * H_SZ + j] = hn;
    c_out[(size_t)b * H_SZ + j] = cn;
  }
}

__global__ void copy2(const float* __restrict__ a, const float* __restrict__ b,
                      float* __restrict__ da, float* __restrict__ db, int n) {
  const int i = blockIdx.x * 256 + threadIdx.x;
  if (i < n) {
    da[i] = a[i];
    db[i] = b[i];
  }
}

extern "C" void kernel_launch(void* const* d_in, const int* in_sizes, int n_in,
                              void* d_out, int out_size, void* d_ws, size_t ws_size,
                              hipStream_t stream) {
  (void)in_sizes; (void)n_in; (void)out_size;
  const float* x = (const float*)d_in[0];
  const float* h0 = (const float*)d_in[1];
  const float* c0 = (const float*)d_in[2];
  const float* reset = (const float*)d_in[3];
  const float* W = (const float*)d_in[4];
  const float* bias = (const float*)d_in[5];
  float* out = (float*)d_out;

  const size_t TB = (size_t)T_STEPS * B_SZ;                // 16384
  const size_t xw_elems = TB * G4;                         // 67,108,864
  const size_t state_elems = (size_t)B_SZ * H_SZ;          // 131,072
  const size_t need = (xw_elems + 2 * state_elems) * sizeof(float);
  float* ws = (float*)d_ws;
  const bool has_xw = ws_size >= need;
  float* xw = ws;
  float* cbuf = has_xw ? (ws + xw_elems) : ws;  // 2 x [B,H] c double-buffer

  if (has_xw) {
    xw_gemm<<<dim3(G4 / 64, (int)(TB / 64)), 256, 0, stream>>>(x, W, bias, xw);
  }

  float* hT = out + TB * H_SZ;
  float* cT = hT + state_elems;

  for (int t = 0; t < T_STEPS; ++t) {
    const float* hp = (t == 0) ? h0 : out + (size_t)(t - 1) * B_SZ * H_SZ;
    const float* cp = (t == 0) ? c0 : cbuf + (size_t)((t - 1) & 1) * state_elems;
    float* ho = out + (size_t)t * B_SZ * H_SZ;
    float* co = cbuf + (size_t)(t & 1) * state_elems;
    if (has_xw) {
      lstm_step<1><<<dim3(32, 8), 256, 0, stream>>>(
          hp, cp, nullptr, xw + (size_t)t * B_SZ * G4, W, bias,
          reset + (size_t)t * B_SZ, ho, co);
    } else {
      lstm_step<0><<<dim3(32, 8), 256, 0, stream>>>(
          hp, cp, x + (size_t)t * B_SZ * D_SZ, nullptr, W, bias,
          reset + (size_t)t * B_SZ, ho, co);
    }
  }

  copy2<<<dim3((int)((state_elems + 255) / 256)), 256, 0, stream>>>(
      out + (TB - B_SZ) * H_SZ,
      cbuf + (size_t)((T_STEPS - 1) & 1) * state_elems,
      hT, cT, (int)state_elems);
}

// Round 2
// 2356.640 us; speedup vs baseline: 4.5673x; 4.5673x over previous
//
#include <hip/hip_runtime.h>
#include <math.h>

#define T_STEPS 128
#define B_SZ 128
#define D_SZ 1024
#define H_SZ 1024
#define G4 4096
#define KW 2048  // rows of W = D+H

typedef __attribute__((ext_vector_type(8))) short bf16x8;
typedef __attribute__((ext_vector_type(4))) float f32x4;
typedef unsigned short ushort_t;
typedef unsigned int uint_t;

__device__ __forceinline__ float sigf(float x) { return 1.0f / (1.0f + __expf(-x)); }

__device__ __forceinline__ ushort_t f2bf(float f) {
  uint_t u = __float_as_uint(f);
  return (ushort_t)((u + 0x7fffu + ((u >> 16) & 1u)) >> 16);
}
__device__ __forceinline__ float bf2f(ushort_t s) {
  return __uint_as_float(((uint_t)s) << 16);
}

// ---------------------------------------------------------------------------
// x fp32 [16384][1024] -> bf16 same layout. 8 elems/thread.
// ---------------------------------------------------------------------------
__global__ __launch_bounds__(256) void convert_x(const float* __restrict__ x,
                                                 ushort_t* __restrict__ xbf) {
  const size_t i8 = ((size_t)blockIdx.x * 256 + threadIdx.x) * 8;
  if (i8 + 8 > (size_t)T_STEPS * B_SZ * D_SZ) return;
  float4 a = *(const float4*)&x[i8];
  float4 b = *(const float4*)&x[i8 + 4];
  ushort_t o[8] = {f2bf(a.x), f2bf(a.y), f2bf(a.z), f2bf(a.w),
                   f2bf(b.x), f2bf(b.y), f2bf(b.z), f2bf(b.w)};
  *(uint4*)&xbf[i8] = *(uint4*)o;
}

// ---------------------------------------------------------------------------
// W fp32 [2048][4096] -> WT bf16 [4096][2048]  (WT[n][k] = W[k][n])
// ---------------------------------------------------------------------------
__global__ __launch_bounds__(256) void transpose_w(const float* __restrict__ W,
                                                   ushort_t* __restrict__ WT) {
  __shared__ float t[32][33];
  const int tx = threadIdx.x & 31;
  const int ty = threadIdx.x >> 5;  // 0..7
  const int k0 = blockIdx.x * 32;
  const int n0 = blockIdx.y * 32;
#pragma unroll
  for (int i = 0; i < 4; ++i)
    t[ty + i * 8][tx] = W[(size_t)(k0 + ty + i * 8) * G4 + n0 + tx];
  __syncthreads();
#pragma unroll
  for (int i = 0; i < 4; ++i)
    WT[(size_t)(n0 + ty + i * 8) * KW + k0 + tx] = f2bf(t[tx][ty + i * 8]);
}

// ---------------------------------------------------------------------------
// hbf0 = bf16(h0 * (1-reset[0])), c0m = c0 * (1-reset[0])
// ---------------------------------------------------------------------------
__global__ __launch_bounds__(256) void init_state(const float* __restrict__ h0,
                                                  const float* __restrict__ c0,
                                                  const float* __restrict__ reset0,
                                                  ushort_t* __restrict__ hbf0,
                                                  float* __restrict__ c0m) {
  const int i = blockIdx.x * 256 + threadIdx.x;
  if (i >= B_SZ * H_SZ) return;
  const float m = 1.0f - reset0[i >> 10];
  hbf0[i] = f2bf(h0[i] * m);
  c0m[i] = c0[i] * m;
}

// ---------------------------------------------------------------------------
// xwbf[m][n] = bf16( bias[n] + sum_k xbf[m][k] * WT[n][k] ),  k in [0,1024)
// 128x128 block tile, 4 waves (2x2), 64x64 per wave, direct-global loads.
// ---------------------------------------------------------------------------
__global__ __launch_bounds__(256) void xw_mfma(const ushort_t* __restrict__ xbf,
                                               const ushort_t* __restrict__ WT,
                                               const float* __restrict__ bias,
                                               ushort_t* __restrict__ xwbf) {
  const int lane = threadIdx.x & 63;
  const int wid = threadIdx.x >> 6;
  const int wr = wid >> 1, wc = wid & 1;
  const int m0 = blockIdx.y * 128 + wr * 64;
  const int n0 = blockIdx.x * 128 + wc * 64;
  const int lr = lane & 15;
  const int lk8 = (lane >> 4) * 8;

  const ushort_t* aptr[4];
  const ushort_t* bptr[4];
#pragma unroll
  for (int mi = 0; mi < 4; ++mi)
    aptr[mi] = xbf + (size_t)(m0 + mi * 16 + lr) * D_SZ + lk8;
#pragma unroll
  for (int ni = 0; ni < 4; ++ni)
    bptr[ni] = WT + (size_t)(n0 + ni * 16 + lr) * KW + lk8;

  f32x4 acc[4][4] = {};
  for (int k0 = 0; k0 < D_SZ; k0 += 32) {
    bf16x8 a[4], b[4];
#pragma unroll
    for (int mi = 0; mi < 4; ++mi) {
      a[mi] = *(const bf16x8*)aptr[mi];
      aptr[mi] += 32;
    }
#pragma unroll
    for (int ni = 0; ni < 4; ++ni) {
      b[ni] = *(const bf16x8*)bptr[ni];
      bptr[ni] += 32;
    }
#pragma unroll
    for (int mi = 0; mi < 4; ++mi)
#pragma unroll
      for (int ni = 0; ni < 4; ++ni)
        acc[mi][ni] = __builtin_amdgcn_mfma_f32_16x16x32_bf16(a[mi], b[ni], acc[mi][ni], 0, 0, 0);
  }

  const int rr = (lane >> 4) * 4;
#pragma unroll
  for (int ni = 0; ni < 4; ++ni) {
    const int n = n0 + ni * 16 + lr;
    const float bn = bias[n];
#pragma unroll
    for (int mi = 0; mi < 4; ++mi) {
#pragma unroll
      for (int r = 0; r < 4; ++r) {
        const int m = m0 + mi * 16 + rr + r;
        xwbf[(size_t)m * G4 + n] = f2bf(acc[mi][ni][r] + bn);
      }
    }
  }
}

// ---------------------------------------------------------------------------
// One LSTM step, MFMA. Grid (64 j-tiles, 4 b-tiles), 256 thr = 4 waves.
// Wave (kh, mh): kh = K-half (512), mh = 16-row half of the 32-row b-tile.
// gates[b][g*1024+j] = xwbf_t + hbf_prev @ Wh ;  Wh[k][n] = WT[n][1024+k]
// ---------------------------------------------------------------------------
__global__ __launch_bounds__(256) void lstm_step_mfma(
    const ushort_t* __restrict__ hbf_prev,  // [128][1024] premasked
    const float* __restrict__ c_prev,       // [128][1024] premasked
    const ushort_t* __restrict__ xwbf_t,    // [128][4096] (bias included)
    const ushort_t* __restrict__ WT,        // [4096][2048]
    const float* __restrict__ reset_next,   // [128] or null
    float* __restrict__ h_out,              // [128][1024]
    ushort_t* __restrict__ hbf_next,        // [128][1024] or null
    float* __restrict__ c_out)              // [128][1024]
{
  const int lane = threadIdx.x & 63;
  const int wid = threadIdx.x >> 6;
  const int kh = wid & 1;
  const int mh = wid >> 1;
  const int jt = blockIdx.x;
  const int bt = blockIdx.y;
  const int lr = lane & 15;
  const int lk8 = (lane >> 4) * 8;

  const int arow = bt * 32 + mh * 16 + lr;
  const int kbase = kh * 512 + lk8;
  const ushort_t* aptr = hbf_prev + (size_t)arow * H_SZ + kbase;
  const ushort_t* bptr[4];
#pragma unroll
  for (int g = 0; g < 4; ++g) {
    const int n = g * H_SZ + jt * 16 + lr;
    bptr[g] = WT + (size_t)n * KW + H_SZ + kbase;  // Wh part: k offset +1024
  }

  f32x4 acc[4] = {};
#pragma unroll 2
  for (int it = 0; it < 16; ++it) {
    bf16x8 a = *(const bf16x8*)aptr;
    aptr += 32;
    bf16x8 b[4];
#pragma unroll
    for (int g = 0; g < 4; ++g) {
      b[g] = *(const bf16x8*)bptr[g];
      bptr[g] += 32;
    }
#pragma unroll
    for (int g = 0; g < 4; ++g)
      acc[g] = __builtin_amdgcn_mfma_f32_16x16x32_bf16(a, b[g], acc[g], 0, 0, 0);
  }

  __shared__ float lds[2][4][16][17];
  const int rr = (lane >> 4) * 4;
  if (kh == 1) {
#pragma unroll
    for (int g = 0; g < 4; ++g)
#pragma unroll
      for (int r = 0; r < 4; ++r) lds[mh][g][rr + r][lr] = acc[g][r];
  }
  __syncthreads();
  if (kh == 0) {
    const int j = jt * 16 + lr;
#pragma unroll
    for (int r = 0; r < 4; ++r) {
      const int b = bt * 32 + mh * 16 + rr + r;
      const size_t xo = (size_t)b * G4 + j;
      float gi = acc[0][r] + lds[mh][0][rr + r][lr] + bf2f(xwbf_t[xo]);
      float gg = acc[1][r] + lds[mh][1][rr + r][lr] + bf2f(xwbf_t[xo + H_SZ]);
      float gf = acc[2][r] + lds[mh][2][rr + r][lr] + bf2f(xwbf_t[xo + 2 * H_SZ]);
      float go = acc[3][r] + lds[mh][3][rr + r][lr] + bf2f(xwbf_t[xo + 3 * H_SZ]);
      const size_t so = (size_t)b * H_SZ + j;
      const float c = c_prev[so];
      const float f = sigf(gf + 1.0f);
      const float cn = f * c + sigf(gi) * tanhf(gg);
      const float hn = sigf(go) * tanhf(cn);
      h_out[so] = hn;
      const float mn = reset_next ? (1.0f - reset_next[b]) : 1.0f;
      if (hbf_next) hbf_next[so] = f2bf(hn * mn);
      c_out[so] = cn * mn;
    }
  }
}

__global__ __launch_bounds__(256) void copy_hT(const float* __restrict__ src,
                                               float* __restrict__ dst) {
  const int i = blockIdx.x * 256 + threadIdx.x;
  if (i < B_SZ * H_SZ) dst[i] = src[i];
}

extern "C" void kernel_launch(void* const* d_in, const int* in_sizes, int n_in,
                              void* d_out, int out_size, void* d_ws, size_t ws_size,
                              hipStream_t stream) {
  (void)in_sizes; (void)n_in; (void)out_size; (void)ws_size;
  const float* x = (const float*)d_in[0];
  const float* h0 = (const float*)d_in[1];
  const float* c0 = (const float*)d_in[2];
  const float* reset = (const float*)d_in[3];
  const float* W = (const float*)d_in[4];
  const float* bias = (const float*)d_in[5];
  float* out = (float*)d_out;

  const size_t TB = (size_t)T_STEPS * B_SZ;       // 16384
  const size_t SE = (size_t)B_SZ * H_SZ;          // 131072

  // ws layout (bytes)
  char* p = (char*)d_ws;
  ushort_t* WT = (ushort_t*)p;            p += (size_t)G4 * KW * 2;       // 16.8MB
  ushort_t* xbf = (ushort_t*)p;           p += TB * D_SZ * 2;             // 33.6MB
  ushort_t* xwbf = (ushort_t*)p;          p += TB * G4 * 2;               // 134.2MB
  ushort_t* hbf0 = (ushort_t*)p;          p += SE * 2;
  ushort_t* hbuf0 = (ushort_t*)p;         p += SE * 2;
  ushort_t* hbuf1 = (ushort_t*)p;         p += SE * 2;
  float* c0m = (float*)p;                 p += SE * 4;
  float* cbuf0 = (float*)p;               p += SE * 4;
  float* cbuf1 = (float*)p;               p += SE * 4;

  convert_x<<<dim3((int)(TB * D_SZ / 8 / 256)), 256, 0, stream>>>(x, xbf);
  transpose_w<<<dim3(KW / 32, G4 / 32), 256, 0, stream>>>(W, WT);
  init_state<<<dim3((int)((SE + 255) / 256)), 256, 0, stream>>>(h0, c0, reset, hbf0, c0m);
  xw_mfma<<<dim3(G4 / 128, (int)(TB / 128)), 256, 0, stream>>>(xbf, WT, bias, xwbf);

  float* hT = out + TB * H_SZ;
  float* cT = hT + SE;
  ushort_t* hbufs[2] = {hbuf0, hbuf1};
  float* cbufs[2] = {cbuf0, cbuf1};

  for (int t = 0; t < T_STEPS; ++t) {
    const ushort_t* hp = (t == 0) ? hbf0 : hbufs[(t - 1) & 1];
    const float* cp = (t == 0) ? c0m : cbufs[(t - 1) & 1];
    float* ho = out + (size_t)t * SE;
    const bool last = (t == T_STEPS - 1);
    ushort_t* hn = last ? nullptr : hbufs[t & 1];
    float* cn = last ? cT : cbufs[t & 1];
    const float* rn = last ? nullptr : (reset + (size_t)(t + 1) * B_SZ);
    lstm_step_mfma<<<dim3(64, 4), 256, 0, stream>>>(
        hp, cp, xwbf + (size_t)t * B_SZ * G4, WT, rn, ho, hn, cn);
  }

  copy_hT<<<dim3((int)((SE + 255) / 256)), 256, 0, stream>>>(
      out + (TB - B_SZ) * H_SZ, hT);
}